// Round 14
// baseline (188.185 us; speedup 1.0000x reference)
//
#include <hip/hip_runtime.h>
#include <hip/hip_bf16.h>
#include <math.h>

// H=2048 NH=16 NG=4 WS=256 SS=128 B=2 N=4096 C=512 HD=32
// out0: (2,4096,2048) f32 ; out1 attn: (4,16,2,16,256,256) f32
// Structural facts used:
//  * repeat+raw-reshape => context vector is 16-fold channel-replicated =>
//    out0 = pv(8192x128) @ WoR(128x2048), WoR = 16-row sums of Wo.
//  * V~ has 2 distinct values per j => PV collapses to [pa,pb] per row/head.
//  * roll(-128) over batch axis (size 2, even shift) is identity.
// R8 lesson: forcing 4 blocks/CU with acc[16] live spills (224->338).
// R12 win: two-pass attn (stats + chunk-recompute) fits (256,4): 221->198.
// R13 win: qkv split-K=2 + f32 exp2f tables: 198->182.5.
// R14: re-test R10's fusion WITHOUT the confound -- tables/WoR ride in the
// qkv dispatch (backfilling its latency-bound blocks); attn flush waits KEPT.

typedef short bf16x8 __attribute__((ext_vector_type(8)));
typedef float f32x4 __attribute__((ext_vector_type(4)));
typedef unsigned short u16x8 __attribute__((ext_vector_type(8)));
typedef unsigned short u16x2 __attribute__((ext_vector_type(2)));

#define AS1 __attribute__((address_space(1)))
#define AS3 __attribute__((address_space(3)))

__device__ __forceinline__ void gload16(const void* g, void* l) {
  __builtin_amdgcn_global_load_lds((const AS1 void*)g, (AS3 void*)l, 16, 0, 0);
}

__device__ __forceinline__ unsigned short f2bf(float f) {
  unsigned u = __float_as_uint(f);
  u += 0x7FFFu + ((u >> 16) & 1u);
  return (unsigned short)(u >> 16);
}

// ---- prep: weight transposes + biaskv only (must precede qkv) ----
// bi<256: T(Wq); <320: T(Wk); <384: T(Wv); ==384: biaskv.
__global__ __launch_bounds__(256) void k_prep(const float* __restrict__ Wq,
                                              const float* __restrict__ Wk,
                                              const float* __restrict__ Wv,
                                              unsigned short* __restrict__ WqT,
                                              unsigned short* __restrict__ WkvT,
                                              const float* __restrict__ bk,
                                              const float* __restrict__ bv,
                                              float* __restrict__ biaskv) {
  __shared__ float tile[32][33];
  const int bi = blockIdx.x;
  const int tid = threadIdx.x;

  if (bi < 384) {
    const float* in;
    unsigned short* out;
    int C, rowOff, tc, tr;
    if (bi < 256) {
      in = Wq; out = WqT; C = 128; rowOff = 0;
      tc = (bi & 3) * 32; tr = (bi >> 2) * 32;
    } else if (bi < 320) {
      int i = bi - 256;
      in = Wk; out = WkvT; C = 32; rowOff = 0;
      tc = 0; tr = i * 32;
    } else {
      int i = bi - 320;
      in = Wv; out = WkvT; C = 32; rowOff = 32;
      tc = 0; tr = i * 32;
    }
    int lx = tid & 31, ly = tid >> 5;
#pragma unroll
    for (int s2 = 0; s2 < 4; ++s2) {
      int rr = ly + s2 * 8;
      tile[rr][lx] = in[(size_t)(tr + rr) * C + tc + lx];
    }
    __syncthreads();
#pragma unroll
    for (int s2 = 0; s2 < 4; ++s2) {
      int cc = ly + s2 * 8;
      out[(size_t)(rowOff + tc + cc) * 2048 + tr + lx] = f2bf(tile[lx][cc]);
    }
    return;
  }
  if (tid < 128) biaskv[tid] = (tid < 32) ? bk[tid] : ((tid < 64) ? bv[tid - 32] : 0.f);
}

// ---- QKV GEMM (split-K=2) + fused aux work (tables / WoR reduce) ----
// x<256: GEMM; y=K-half, z=problem(q/kv). Bias folded into y==0 partial.
// x>=256: aux = (x-256)*4 + z*2 + y in [0,3072):
//   aux<2048 -> RoPE table block (512 entries); else WoR block (1024 total).
__global__ __launch_bounds__(256) void k_qkv(const float* __restrict__ A0,
                                             const unsigned short* __restrict__ B0,
                                             float* __restrict__ C0a,
                                             float* __restrict__ C0b,
                                             const float* __restrict__ bias0,
                                             const float* __restrict__ A1,
                                             const unsigned short* __restrict__ B1,
                                             float* __restrict__ C1a,
                                             float* __restrict__ C1b,
                                             const float* __restrict__ bias1,
                                             float* __restrict__ cosT,
                                             float* __restrict__ sinT,
                                             const float* __restrict__ Wo,
                                             unsigned short* __restrict__ WoR,
                                             int K) {
  const int tid = threadIdx.x;
  if (blockIdx.x >= 256) {
    const int aux = (blockIdx.x - 256) * 4 + blockIdx.z * 2 + blockIdx.y;
    if (aux < 2048) {  // RoPE tables: 2 entries/thread (adjacent idx, same p)
      int e = aux * 512 + tid * 2;
      int p = e >> 8, idx = e & 255;
      float i0 = exp2f((float)idx * -0.05190512648261504f);   // 10000^(-idx/256)
      float i1 = exp2f((float)(idx + 1) * -0.05190512648261504f);
      float s0, c0, s1, c1;
      sincosf((float)p * i0, &s0, &c0);
      sincosf((float)p * i1, &s1, &c1);
      *(float2*)&cosT[e] = make_float2(c0, c1);
      *(float2*)&sinT[e] = make_float2(s0, s1);
    } else {  // WoR[c][kk] = bf16(sum_{d<16} Wo[base+d][c])
      int i = aux - 2048;
      const int kk = i >> 3;
      const int c = (i & 7) * 256 + tid;
      const int base = (kk >> 5) * 512 + ((kk >> 1) & 15) * 32 + (kk & 1) * 16;
      float s = 0.f;
#pragma unroll
      for (int d = 0; d < 16; ++d) s += Wo[(size_t)(base + d) * 2048 + c];
      WoR[(size_t)c * 128 + kk] = f2bf(s);
    }
    return;
  }

  const float* A = blockIdx.z ? A1 : A0;
  const unsigned short* Bt = blockIdx.z ? B1 : B0;
  float* C = blockIdx.z ? (blockIdx.y ? C1b : C1a) : (blockIdx.y ? C0b : C0a);
  const float* bias = blockIdx.z ? bias1 : bias0;
  const int khalf = K >> 1;
  const int k0 = blockIdx.y * khalf, k1 = k0 + khalf;

  __shared__ unsigned short Al[2][32 * 32];
  __shared__ unsigned short Bl[2][128 * 32];
  const int wave = tid >> 6, lane = tid & 63;
  const int wm = wave >> 1, wn = wave & 1;
  f32x4 acc[4] = {};
  const int lrow = lane & 15, kq = (lane >> 4) * 8;
  const size_t abase = (size_t)blockIdx.x * 32;
  const int rB = lane >> 2, cB = (lane & 3) * 8;
  const int ar = tid >> 3, ac = (tid & 7) * 4;
  const float* aptr = A + (abase + ar) * (size_t)K + ac;

#define QKV_STAGEB(buf, kt)                                                     \
  {                                                                             \
    gload16(Bt + (size_t)(wave * 16 + rB) * K + (kt) + cB,                      \
            &Bl[buf][(wave * 16) * 32]);                                        \
    gload16(Bt + (size_t)(64 + wave * 16 + rB) * K + (kt) + cB,                 \
            &Bl[buf][(64 + wave * 16) * 32]);                                   \
  }

  float4 r0 = *(const float4*)(aptr + k0);
  QKV_STAGEB(0, k0);
  *(ushort4*)&Al[0][ar * 32 + ac] =
      make_ushort4(f2bf(r0.x), f2bf(r0.y), f2bf(r0.z), f2bf(r0.w));
  __syncthreads();

  int cur = 0;
  for (int kt = k0; kt < k1; kt += 32) {
    const bool more = (kt + 32) < k1;
    if (more) {
      r0 = *(const float4*)(aptr + kt + 32);
      QKV_STAGEB(cur ^ 1, kt + 32);
    }
    bf16x8 af = *(const bf16x8*)&Al[cur][(wm * 16 + lrow) * 32 + kq];
    bf16x8 bg[4];
#pragma unroll
    for (int n = 0; n < 4; ++n)
      bg[n] = *(const bf16x8*)&Bl[cur][(wn * 64 + n * 16 + lrow) * 32 + kq];
#pragma unroll
    for (int n = 0; n < 4; ++n)
      acc[n] = __builtin_amdgcn_mfma_f32_16x16x32_bf16(af, bg[n], acc[n], 0, 0, 0);
    if (more)
      *(ushort4*)&Al[cur ^ 1][ar * 32 + ac] =
          make_ushort4(f2bf(r0.x), f2bf(r0.y), f2bf(r0.z), f2bf(r0.w));
    __syncthreads();
    cur ^= 1;
  }
#undef QKV_STAGEB
  const int mb = (int)abase + wm * 16;
#pragma unroll
  for (int n = 0; n < 4; ++n)
#pragma unroll
    for (int r2 = 0; r2 < 4; ++r2) {
      int row = mb + (lane >> 4) * 4 + r2;
      int col = wn * 64 + n * 16 + lrow;
      float bcol = blockIdx.y ? 0.f : bias[col];
      C[(size_t)row * 128 + col] = acc[n][r2] + bcol;
    }
}

// ---- bf16 MFMA GEMM (out = pv @ WoR + bo), 2-phase double-buffered ----
template <int BM, int BN>
__global__ __launch_bounds__(256) void k_gemm(const unsigned short* __restrict__ A,
                                              const unsigned short* __restrict__ Bt,
                                              float* __restrict__ C,
                                              const float* __restrict__ bias,
                                              int M, int N, int K) {
  __shared__ unsigned short Al[2][BM * 32];
  __shared__ unsigned short Bl[2][BN * 32];
  const int tid = threadIdx.x;
  const int wave = tid >> 6, lane = tid & 63;
  const int wm = wave >> 1, wn = wave & 1;
  constexpr int FM = BM / 32, FN = BN / 32;
  f32x4 acc[FM][FN] = {};
  const int lrow = lane & 15, kq = (lane >> 4) * 8;
  const size_t abase = (size_t)blockIdx.x * BM;
  const size_t bbase = (size_t)blockIdx.y * BN;
  const int rA = lane >> 2, cA = (lane & 3) * 8;

#define STAGE(buf, kt)                                                                \
  {                                                                                   \
    _Pragma("unroll") for (int c2 = 0; c2 < BM / 64; ++c2) {                          \
      int rr = (c2 * 4 + wave) * 16 + rA;                                             \
      gload16(A + (abase + rr) * K + (kt) + cA, &Al[buf][(c2 * 4 + wave) * 512]);     \
    }                                                                                 \
    _Pragma("unroll") for (int c2 = 0; c2 < BN / 64; ++c2) {                          \
      int rr = (c2 * 4 + wave) * 16 + rA;                                             \
      gload16(Bt + (bbase + rr) * K + (kt) + cA, &Bl[buf][(c2 * 4 + wave) * 512]);    \
    }                                                                                 \
  }

  STAGE(0, 0);
  __syncthreads();
  int cur = 0;
  for (int kt = 0; kt < K; kt += 32) {
    if (kt + 32 < K) STAGE(cur ^ 1, kt + 32);
    bf16x8 af[FM], bg[FN];
#pragma unroll
    for (int m = 0; m < FM; ++m)
      af[m] = *(const bf16x8*)&Al[cur][(wm * (BM / 2) + m * 16 + lrow) * 32 + kq];
#pragma unroll
    for (int n = 0; n < FN; ++n)
      bg[n] = *(const bf16x8*)&Bl[cur][(wn * (BN / 2) + n * 16 + lrow) * 32 + kq];
#pragma unroll
    for (int m = 0; m < FM; ++m)
#pragma unroll
      for (int n = 0; n < FN; ++n)
        acc[m][n] = __builtin_amdgcn_mfma_f32_16x16x32_bf16(af[m], bg[n], acc[m][n], 0, 0, 0);
    __syncthreads();
    cur ^= 1;
  }
#undef STAGE
  const int mb = blockIdx.x * BM + wm * (BM / 2);
  const int nb = blockIdx.y * BN + wn * (BN / 2);
#pragma unroll
  for (int m = 0; m < FM; ++m)
#pragma unroll
    for (int n = 0; n < FN; ++n)
#pragma unroll
      for (int r2 = 0; r2 < 4; ++r2) {
        int row = mb + m * 16 + (lane >> 4) * 4 + r2;
        int col = nb + n * 16 + lrow;
        float v = acc[m][n][r2] + bias[col];
        __builtin_nontemporal_store(v, &C[(size_t)row * N + col]);
      }
}

// ---- attention: two-pass, 4 blocks/CU (R12/R13 structure, UNCHANGED) ----
__global__ __launch_bounds__(256, 4) void k_attn(const float* __restrict__ qbufA,
                                                 const float* __restrict__ qbufB,
                                                 const float* __restrict__ kvbufA,
                                                 const float* __restrict__ kvbufB,
                                                 const float* __restrict__ cosT,
                                                 const float* __restrict__ sinT,
                                                 float* __restrict__ attn_out,
                                                 unsigned short* __restrict__ pv_out) {
  __shared__ unsigned short Kb[256 * 32];   // 16 KB bf16 K~
  __shared__ float stage[4][1088];          // 17408 B: Q~ overlay, then P staging
  __shared__ float qkraw[2][16][32];        // 4 KB raw q/k
  __shared__ float vpair[512];              // 2 KB V pairs
  unsigned short* qtile = (unsigned short*)&stage[0][0];  // 256x32 bf16 = 16 KB

  const int t = threadIdx.x;
  const int unit = blockIdx.x;
  const int h = unit & 15, b = (unit >> 4) & 1, w = (unit >> 5) & 15, g = unit >> 9;
  const int row0 = b * 4096 + w * 256 + 16 * h;
  const int p0 = w * 256 + 16 * h;

  for (int e = t; e < 512; e += 256) {
    int r = e >> 5, ch = e & 31;
    size_t gi = (size_t)(row0 + r) * 128;
    qkraw[0][r][ch] = qbufA[gi + g * 32 + ch] + qbufB[gi + g * 32 + ch];
    qkraw[1][r][ch] = kvbufA[gi + ch] + kvbufB[gi + ch];
    vpair[r * 32 + ch] = kvbufA[gi + 32 + ch] + kvbufB[gi + 32 + ch];
  }
  __syncthreads();

  {  // thread t builds micro-row t of Q~ (into qtile) and K~ (into Kb)
    const int r = t >> 4, cb = t & 15;
    const int ch = 2 * cb;
    const int po = (cb < 8) ? 16 : -16;
    const float sg = (cb < 8) ? -1.f : 1.f;
    const float4* c4 = (const float4*)(cosT + (size_t)(p0 + r) * 256 + 32 * (cb & 7));
    const float4* s4 = (const float4*)(sinT + (size_t)(p0 + r) * 256 + 32 * (cb & 7));
    float qa0 = qkraw[0][r][ch], qa1 = qkraw[0][r][ch + 1];
    float qp0 = qkraw[0][r][ch + po], qp1 = qkraw[0][r][ch + po + 1];
    float ka0 = qkraw[1][r][ch], ka1 = qkraw[1][r][ch + 1];
    float kp0 = qkraw[1][r][ch + po], kp1 = qkraw[1][r][ch + po + 1];
    const float rs = 0.044194173824159216f;  // 1/sqrt(512)
    unsigned short qs[32], ks[32];
#pragma unroll
    for (int dq = 0; dq < 8; ++dq) {
      float4 cc = c4[dq], ss = s4[dq];
      float qa = (dq < 4) ? qa0 : qa1, qp = (dq < 4) ? qp0 : qp1;
      float ka = (dq < 4) ? ka0 : ka1, kp = (dq < 4) ? kp0 : kp1;
      qs[dq * 4 + 0] = f2bf((qa * cc.x + sg * qp * ss.x) * rs);
      qs[dq * 4 + 1] = f2bf((qa * cc.y + sg * qp * ss.y) * rs);
      qs[dq * 4 + 2] = f2bf((qa * cc.z + sg * qp * ss.z) * rs);
      qs[dq * 4 + 3] = f2bf((qa * cc.w + sg * qp * ss.w) * rs);
      ks[dq * 4 + 0] = f2bf(ka * cc.x + sg * kp * ss.x);
      ks[dq * 4 + 1] = f2bf(ka * cc.y + sg * kp * ss.y);
      ks[dq * 4 + 2] = f2bf(ka * cc.z + sg * kp * ss.z);
      ks[dq * 4 + 3] = f2bf(ka * cc.w + sg * kp * ss.w);
    }
#pragma unroll
    for (int q4 = 0; q4 < 4; ++q4) {
      *(u16x8*)&qtile[t * 32 + q4 * 8] = *(u16x8*)&qs[q4 * 8];
      *(u16x8*)&Kb[t * 32 + q4 * 8] = *(u16x8*)&ks[q4 * 8];
    }
  }
  __syncthreads();

  const int wv = t >> 6, lane = t & 63;
  const int lm = lane & 15, lq = lane >> 4;
  const int kq = lq * 8;
  const size_t abase = (size_t)unit * 65536;
  float* stw = &stage[wv][0];

  // preload this lane's 4 Q-fragments (32 VGPR), then release stage buffer
  bf16x8 bQf[4];
#pragma unroll
  for (int mt = 0; mt < 4; ++mt)
    bQf[mt] = *(const bf16x8*)&qtile[((wv * 4 + mt) * 16 + lm) * 32 + kq];
  __syncthreads();  // qtile dead; stage becomes per-wave P staging

#pragma unroll
  for (int mt = 0; mt < 4; ++mt) {
    const int iT = wv * 4 + mt;
    const int i = iT * 16 + lm;  // this lane's query row

    // ---- pass A: stats only (one MFMA result live at a time) ----
    float ls = 0.f, pa = 0.f, pb = 0.f;
#pragma unroll
    for (int nt = 0; nt < 16; ++nt) {
      bf16x8 aK = *(const bf16x8*)&Kb[(nt * 16 + lm) * 32 + kq];
      f32x4 z = {0.f, 0.f, 0.f, 0.f};
      f32x4 s4 = __builtin_amdgcn_mfma_f32_16x16x32_bf16(aK, bQf[mt], z, 0, 0, 0);
      float4 v01 = *(const float4*)&vpair[nt * 32 + lq * 8];
      float4 v23 = *(const float4*)&vpair[nt * 32 + lq * 8 + 4];
      const int j0 = nt * 16 + lq * 4;
      float e0 = __expf((j0 + 0 <= i) ? s4[0] : 0.f);
      float e1 = __expf((j0 + 1 <= i) ? s4[1] : 0.f);
      float e2 = __expf((j0 + 2 <= i) ? s4[2] : 0.f);
      float e3 = __expf((j0 + 3 <= i) ? s4[3] : 0.f);
      ls += (e0 + e1) + (e2 + e3);
      pa += e0 * v01.x + e1 * v01.z + e2 * v23.x + e3 * v23.z;
      pb += e0 * v01.y + e1 * v01.w + e2 * v23.y + e3 * v23.w;
    }
    ls += __shfl_xor(ls, 16);
    ls += __shfl_xor(ls, 32);
    pa += __shfl_xor(pa, 16);
    pa += __shfl_xor(pa, 32);
    pb += __shfl_xor(pb, 16);
    pb += __shfl_xor(pb, 32);
    const float invl = 1.f / ls;

    if (lq == 0) {  // pv row entry: cols g*32 + h*2 + {0,1}
      u16x2 pvv = {f2bf(pa * invl), f2bf(pb * invl)};
      *(u16x2*)&pv_out[(size_t)(b * 4096 + w * 256 + i) * 128 + g * 32 + h * 2] = pvv;
    }

    // ---- pass B: recompute per 64-col chunk, stage, coalesced NT flush ----
#pragma unroll
    for (int nc = 0; nc < 4; ++nc) {
#pragma unroll
      for (int nt2 = 0; nt2 < 4; ++nt2) {
        int nt = nc * 4 + nt2;
        bf16x8 aK = *(const bf16x8*)&Kb[(nt * 16 + lm) * 32 + kq];
        f32x4 z = {0.f, 0.f, 0.f, 0.f};
        f32x4 s4 = __builtin_amdgcn_mfma_f32_16x16x32_bf16(aK, bQf[mt], z, 0, 0, 0);
        const int j0 = nt * 16 + lq * 4;
        f32x4 p4;
        p4[0] = __expf((j0 + 0 <= i) ? s4[0] : 0.f) * invl;
        p4[1] = __expf((j0 + 1 <= i) ? s4[1] : 0.f) * invl;
        p4[2] = __expf((j0 + 2 <= i) ? s4[2] : 0.f) * invl;
        p4[3] = __expf((j0 + 3 <= i) ? s4[3] : 0.f) * invl;
        int phys = (nt2 * 4 + lq + lm) & 15;  // rotate-slot swizzle
        *(f32x4*)&stw[lm * 68 + phys * 4] = p4;
      }
      asm volatile("s_waitcnt lgkmcnt(0)" ::: "memory");
      __builtin_amdgcn_sched_barrier(0);
#pragma unroll
      for (int rb = 0; rb < 4; ++rb) {
        int rr = rb * 4 + lq;   // row within tile
        int c = lm;             // 16B slot within 64-col chunk
        int phys = (c + rr) & 15;
        f32x4 pvv = *(const f32x4*)&stw[rr * 68 + phys * 4];
        f32x4* gp = (f32x4*)&attn_out[abase + (size_t)(iT * 16 + rr) * 256 + nc * 64 + c * 4];
        __builtin_nontemporal_store(pvv, gp);
      }
      asm volatile("s_waitcnt lgkmcnt(0)" ::: "memory");
      __builtin_amdgcn_sched_barrier(0);
    }
  }
}

extern "C" void kernel_launch(void* const* d_in, const int* in_sizes, int n_in,
                              void* d_out, int out_size, void* d_ws, size_t ws_size,
                              hipStream_t stream) {
  const float* inputs  = (const float*)d_in[0];
  const float* context = (const float*)d_in[1];
  const float* Wq = (const float*)d_in[3];
  const float* bq = (const float*)d_in[4];
  const float* Wk = (const float*)d_in[5];
  const float* bk = (const float*)d_in[6];
  const float* Wv = (const float*)d_in[7];
  const float* bv = (const float*)d_in[8];
  const float* Wo = (const float*)d_in[9];
  const float* bo = (const float*)d_in[10];
  float* out = (float*)d_out;
  float* attn_out = out + 16777216;

  char* wsb = (char*)d_ws;
  size_t o = 0;
  float* cosT = (float*)(wsb + o);            o += 4194304;
  float* sinT = (float*)(wsb + o);            o += 4194304;
  unsigned short* WqT  = (unsigned short*)(wsb + o); o += 524288;   // 128x2048 bf16
  unsigned short* WkvT = (unsigned short*)(wsb + o); o += 524288;   // 128x2048 (rows 64+ stale, unused)
  unsigned short* WoR  = (unsigned short*)(wsb + o); o += 524288;   // 2048x128 bf16 reduced Wo
  float* qbufA  = (float*)(wsb + o);          o += 4194304;
  float* qbufB  = (float*)(wsb + o);          o += 4194304;
  float* kvbufA = (float*)(wsb + o);          o += 4194304;
  float* kvbufB = (float*)(wsb + o);          o += 4194304;
  unsigned short* pv = (unsigned short*)(wsb + o); o += 2097152;    // 8192x128 bf16
  float* biaskv = (float*)(wsb + o);          o += 512;

  // weight transposes + biaskv (small; must precede qkv)
  k_prep<<<385, 256, 0, stream>>>(Wq, Wk, Wv, WqT, WkvT, bk, bv, biaskv);

  // split-K=2 QKV GEMM + aux blocks (tables / WoR) backfilling:
  // x<256 GEMM (x,y,z); x in [256,1024) aux -> 768*4 = 3072 aux blocks.
  k_qkv<<<dim3(1024, 2, 2), 256, 0, stream>>>(
      inputs, WqT, qbufA, qbufB, bq, context, WkvT, kvbufA, kvbufB, biaskv,
      cosT, sinT, Wo, WoR, 2048);

  k_attn<<<2048, 256, 0, stream>>>(qbufA, qbufB, kvbufA, kvbufB,
                                   cosT, sinT, attn_out, pv);

  // out = pv @ WoR + bo: M=8192 N=2048 K=128 (16x reduced)
  k_gemm<128, 128><<<dim3(64, 16), 256, 0, stream>>>(pv, WoR, out, bo, 8192, 2048, 128);
}

// Round 15
// 182.318 us; speedup vs baseline: 1.0322x; 1.0322x over previous
//
#include <hip/hip_runtime.h>
#include <hip/hip_bf16.h>
#include <math.h>

// H=2048 NH=16 NG=4 WS=256 SS=128 B=2 N=4096 C=512 HD=32
// out0: (2,4096,2048) f32 ; out1 attn: (4,16,2,16,256,256) f32
// Structural facts used:
//  * repeat+raw-reshape => context vector is 16-fold channel-replicated =>
//    out0 = pv(8192x128) @ WoR(128x2048), WoR = 16-row sums of Wo.
//  * V~ has 2 distinct values per j => PV collapses to [pa,pb] per row/head.
//  * roll(-128) over batch axis (size 2, even shift) is identity.
// R8 lesson: forcing 4 blocks/CU with acc[16] live spills (224->338).
// R12 win: two-pass attn (stats + chunk-recompute) fits (256,4): 221->198.
// R13 win: qkv split-K=2 + f32 exp2f tables: 198->182.5. (MEASURED OPTIMUM)
// R14 lesson: fusing tables/WoR into the qkv dispatch extends its makespan
// (attn waits on ALL its blocks): 182.5->188.2. Keep prep separate.

typedef short bf16x8 __attribute__((ext_vector_type(8)));
typedef float f32x4 __attribute__((ext_vector_type(4)));
typedef unsigned short u16x8 __attribute__((ext_vector_type(8)));
typedef unsigned short u16x2 __attribute__((ext_vector_type(2)));

#define AS1 __attribute__((address_space(1)))
#define AS3 __attribute__((address_space(3)))

__device__ __forceinline__ void gload16(const void* g, void* l) {
  __builtin_amdgcn_global_load_lds((const AS1 void*)g, (AS3 void*)l, 16, 0, 0);
}

__device__ __forceinline__ unsigned short f2bf(float f) {
  unsigned u = __float_as_uint(f);
  u += 0x7FFFu + ((u >> 16) & 1u);
  return (unsigned short)(u >> 16);
}

// ---- fused prep: tables | transpose Wq/Wk/Wv | reduce Wo | biaskv ----
__global__ __launch_bounds__(256) void k_prep(float* __restrict__ cosT,
                                              float* __restrict__ sinT,
                                              const float* __restrict__ Wq,
                                              const float* __restrict__ Wk,
                                              const float* __restrict__ Wv,
                                              unsigned short* __restrict__ WqT,
                                              unsigned short* __restrict__ WkvT,
                                              const float* __restrict__ Wo,
                                              unsigned short* __restrict__ WoR,
                                              const float* __restrict__ bk,
                                              const float* __restrict__ bv,
                                              float* __restrict__ biaskv) {
  __shared__ float tile[32][33];
  const int bi = blockIdx.x;
  const int tid = threadIdx.x;

  if (bi < 4096) {  // RoPE tables (f32 exp2f: matches the f32 reference)
    int t = bi * 256 + tid;
    int p = t >> 8, idx = t & 255;
    float invf = exp2f((float)idx * -0.05190512648261504f);  // 10000^(-idx/256)
    float ang = (float)p * invf;
    float s, c;
    sincosf(ang, &s, &c);
    cosT[t] = c;
    sinT[t] = s;
    return;
  }
  if (bi < 4480) {  // transposes: f32 [2048][C] -> bf16 [rowOff+C][2048]
    const float* in;
    unsigned short* out;
    int C, rowOff, tc, tr;
    if (bi < 4352) {
      int i = bi - 4096;
      in = Wq; out = WqT; C = 128; rowOff = 0;
      tc = (i & 3) * 32; tr = (i >> 2) * 32;
    } else if (bi < 4416) {
      int i = bi - 4352;
      in = Wk; out = WkvT; C = 32; rowOff = 0;
      tc = 0; tr = i * 32;
    } else {
      int i = bi - 4416;
      in = Wv; out = WkvT; C = 32; rowOff = 32;
      tc = 0; tr = i * 32;
    }
    int lx = tid & 31, ly = tid >> 5;
#pragma unroll
    for (int s2 = 0; s2 < 4; ++s2) {
      int rr = ly + s2 * 8;
      tile[rr][lx] = in[(size_t)(tr + rr) * C + tc + lx];
    }
    __syncthreads();
#pragma unroll
    for (int s2 = 0; s2 < 4; ++s2) {
      int cc = ly + s2 * 8;
      out[(size_t)(rowOff + tc + cc) * 2048 + tr + lx] = f2bf(tile[lx][cc]);
    }
    return;
  }
  if (bi < 5504) {  // WoR[c][kk] = bf16(sum_{d<16} Wo[base+d][c])
    int i = bi - 4480;
    const int kk = i >> 3;
    const int c = (i & 7) * 256 + tid;
    const int base = (kk >> 5) * 512 + ((kk >> 1) & 15) * 32 + (kk & 1) * 16;
    float s = 0.f;
#pragma unroll
    for (int d = 0; d < 16; ++d) s += Wo[(size_t)(base + d) * 2048 + c];
    WoR[(size_t)c * 128 + kk] = f2bf(s);
    return;
  }
  if (tid < 128) biaskv[tid] = (tid < 32) ? bk[tid] : ((tid < 64) ? bv[tid - 32] : 0.f);
}

// ---- QKV GEMM, split-K=2: y picks K-half, each half -> own partial buffer.
// z=0: q=inputs@WqT; z=1: kv=context@WkvT. Bias folded into y==0 partial.
// attn sums the partials at load time (deterministic, no atomics).
__global__ __launch_bounds__(256) void k_qkv(const float* __restrict__ A0,
                                             const unsigned short* __restrict__ B0,
                                             float* __restrict__ C0a,
                                             float* __restrict__ C0b,
                                             const float* __restrict__ bias0,
                                             const float* __restrict__ A1,
                                             const unsigned short* __restrict__ B1,
                                             float* __restrict__ C1a,
                                             float* __restrict__ C1b,
                                             const float* __restrict__ bias1,
                                             int K) {
  const float* A = blockIdx.z ? A1 : A0;
  const unsigned short* Bt = blockIdx.z ? B1 : B0;
  float* C = blockIdx.z ? (blockIdx.y ? C1b : C1a) : (blockIdx.y ? C0b : C0a);
  const float* bias = blockIdx.z ? bias1 : bias0;
  const int khalf = K >> 1;
  const int k0 = blockIdx.y * khalf, k1 = k0 + khalf;

  __shared__ unsigned short Al[2][32 * 32];
  __shared__ unsigned short Bl[2][128 * 32];
  const int tid = threadIdx.x;
  const int wave = tid >> 6, lane = tid & 63;
  const int wm = wave >> 1, wn = wave & 1;
  f32x4 acc[4] = {};
  const int lrow = lane & 15, kq = (lane >> 4) * 8;
  const size_t abase = (size_t)blockIdx.x * 32;
  const int rB = lane >> 2, cB = (lane & 3) * 8;
  const int ar = tid >> 3, ac = (tid & 7) * 4;
  const float* aptr = A + (abase + ar) * (size_t)K + ac;

#define QKV_STAGEB(buf, kt)                                                     \
  {                                                                             \
    gload16(Bt + (size_t)(wave * 16 + rB) * K + (kt) + cB,                      \
            &Bl[buf][(wave * 16) * 32]);                                        \
    gload16(Bt + (size_t)(64 + wave * 16 + rB) * K + (kt) + cB,                 \
            &Bl[buf][(64 + wave * 16) * 32]);                                   \
  }

  float4 r0 = *(const float4*)(aptr + k0);
  QKV_STAGEB(0, k0);
  *(ushort4*)&Al[0][ar * 32 + ac] =
      make_ushort4(f2bf(r0.x), f2bf(r0.y), f2bf(r0.z), f2bf(r0.w));
  __syncthreads();

  int cur = 0;
  for (int kt = k0; kt < k1; kt += 32) {
    const bool more = (kt + 32) < k1;
    if (more) {
      r0 = *(const float4*)(aptr + kt + 32);
      QKV_STAGEB(cur ^ 1, kt + 32);
    }
    bf16x8 af = *(const bf16x8*)&Al[cur][(wm * 16 + lrow) * 32 + kq];
    bf16x8 bg[4];
#pragma unroll
    for (int n = 0; n < 4; ++n)
      bg[n] = *(const bf16x8*)&Bl[cur][(wn * 64 + n * 16 + lrow) * 32 + kq];
#pragma unroll
    for (int n = 0; n < 4; ++n)
      acc[n] = __builtin_amdgcn_mfma_f32_16x16x32_bf16(af, bg[n], acc[n], 0, 0, 0);
    if (more)
      *(ushort4*)&Al[cur ^ 1][ar * 32 + ac] =
          make_ushort4(f2bf(r0.x), f2bf(r0.y), f2bf(r0.z), f2bf(r0.w));
    __syncthreads();
    cur ^= 1;
  }
#undef QKV_STAGEB
  const int mb = (int)abase + wm * 16;
#pragma unroll
  for (int n = 0; n < 4; ++n)
#pragma unroll
    for (int r2 = 0; r2 < 4; ++r2) {
      int row = mb + (lane >> 4) * 4 + r2;
      int col = wn * 64 + n * 16 + lrow;
      float bcol = blockIdx.y ? 0.f : bias[col];
      C[(size_t)row * 128 + col] = acc[n][r2] + bcol;
    }
}

// ---- bf16 MFMA GEMM (out = pv @ WoR + bo), 2-phase double-buffered ----
template <int BM, int BN>
__global__ __launch_bounds__(256) void k_gemm(const unsigned short* __restrict__ A,
                                              const unsigned short* __restrict__ Bt,
                                              float* __restrict__ C,
                                              const float* __restrict__ bias,
                                              int M, int N, int K) {
  __shared__ unsigned short Al[2][BM * 32];
  __shared__ unsigned short Bl[2][BN * 32];
  const int tid = threadIdx.x;
  const int wave = tid >> 6, lane = tid & 63;
  const int wm = wave >> 1, wn = wave & 1;
  constexpr int FM = BM / 32, FN = BN / 32;
  f32x4 acc[FM][FN] = {};
  const int lrow = lane & 15, kq = (lane >> 4) * 8;
  const size_t abase = (size_t)blockIdx.x * BM;
  const size_t bbase = (size_t)blockIdx.y * BN;
  const int rA = lane >> 2, cA = (lane & 3) * 8;

#define STAGE(buf, kt)                                                                \
  {                                                                                   \
    _Pragma("unroll") for (int c2 = 0; c2 < BM / 64; ++c2) {                          \
      int rr = (c2 * 4 + wave) * 16 + rA;                                             \
      gload16(A + (abase + rr) * K + (kt) + cA, &Al[buf][(c2 * 4 + wave) * 512]);     \
    }                                                                                 \
    _Pragma("unroll") for (int c2 = 0; c2 < BN / 64; ++c2) {                          \
      int rr = (c2 * 4 + wave) * 16 + rA;                                             \
      gload16(Bt + (bbase + rr) * K + (kt) + cA, &Bl[buf][(c2 * 4 + wave) * 512]);    \
    }                                                                                 \
  }

  STAGE(0, 0);
  __syncthreads();
  int cur = 0;
  for (int kt = 0; kt < K; kt += 32) {
    if (kt + 32 < K) STAGE(cur ^ 1, kt + 32);
    bf16x8 af[FM], bg[FN];
#pragma unroll
    for (int m = 0; m < FM; ++m)
      af[m] = *(const bf16x8*)&Al[cur][(wm * (BM / 2) + m * 16 + lrow) * 32 + kq];
#pragma unroll
    for (int n = 0; n < FN; ++n)
      bg[n] = *(const bf16x8*)&Bl[cur][(wn * (BN / 2) + n * 16 + lrow) * 32 + kq];
#pragma unroll
    for (int m = 0; m < FM; ++m)
#pragma unroll
      for (int n = 0; n < FN; ++n)
        acc[m][n] = __builtin_amdgcn_mfma_f32_16x16x32_bf16(af[m], bg[n], acc[m][n], 0, 0, 0);
    __syncthreads();
    cur ^= 1;
  }
#undef STAGE
  const int mb = blockIdx.x * BM + wm * (BM / 2);
  const int nb = blockIdx.y * BN + wn * (BN / 2);
#pragma unroll
  for (int m = 0; m < FM; ++m)
#pragma unroll
    for (int n = 0; n < FN; ++n)
#pragma unroll
      for (int r2 = 0; r2 < 4; ++r2) {
        int row = mb + m * 16 + (lane >> 4) * 4 + r2;
        int col = nb + n * 16 + lrow;
        float v = acc[m][n][r2] + bias[col];
        __builtin_nontemporal_store(v, &C[(size_t)row * N + col]);
      }
}

// ---- attention: two-pass, 4 blocks/CU (R12 structure) ----
// Loads sum the two qkv split-K partials. Pass A: stream mfma->exp->stats.
// Pass B: recompute per 64-col chunk, LDS-stage, 256B-aligned NT flush.
__global__ __launch_bounds__(256, 4) void k_attn(const float* __restrict__ qbufA,
                                                 const float* __restrict__ qbufB,
                                                 const float* __restrict__ kvbufA,
                                                 const float* __restrict__ kvbufB,
                                                 const float* __restrict__ cosT,
                                                 const float* __restrict__ sinT,
                                                 float* __restrict__ attn_out,
                                                 unsigned short* __restrict__ pv_out) {
  __shared__ unsigned short Kb[256 * 32];   // 16 KB bf16 K~
  __shared__ float stage[4][1088];          // 17408 B: Q~ overlay, then P staging
  __shared__ float qkraw[2][16][32];        // 4 KB raw q/k
  __shared__ float vpair[512];              // 2 KB V pairs
  unsigned short* qtile = (unsigned short*)&stage[0][0];  // 256x32 bf16 = 16 KB

  const int t = threadIdx.x;
  const int unit = blockIdx.x;
  const int h = unit & 15, b = (unit >> 4) & 1, w = (unit >> 5) & 15, g = unit >> 9;
  const int row0 = b * 4096 + w * 256 + 16 * h;
  const int p0 = w * 256 + 16 * h;

  for (int e = t; e < 512; e += 256) {
    int r = e >> 5, ch = e & 31;
    size_t gi = (size_t)(row0 + r) * 128;
    qkraw[0][r][ch] = qbufA[gi + g * 32 + ch] + qbufB[gi + g * 32 + ch];
    qkraw[1][r][ch] = kvbufA[gi + ch] + kvbufB[gi + ch];
    vpair[r * 32 + ch] = kvbufA[gi + 32 + ch] + kvbufB[gi + 32 + ch];
  }
  __syncthreads();

  {  // thread t builds micro-row t of Q~ (into qtile) and K~ (into Kb)
    const int r = t >> 4, cb = t & 15;
    const int ch = 2 * cb;
    const int po = (cb < 8) ? 16 : -16;
    const float sg = (cb < 8) ? -1.f : 1.f;
    const float4* c4 = (const float4*)(cosT + (size_t)(p0 + r) * 256 + 32 * (cb & 7));
    const float4* s4 = (const float4*)(sinT + (size_t)(p0 + r) * 256 + 32 * (cb & 7));
    float qa0 = qkraw[0][r][ch], qa1 = qkraw[0][r][ch + 1];
    float qp0 = qkraw[0][r][ch + po], qp1 = qkraw[0][r][ch + po + 1];
    float ka0 = qkraw[1][r][ch], ka1 = qkraw[1][r][ch + 1];
    float kp0 = qkraw[1][r][ch + po], kp1 = qkraw[1][r][ch + po + 1];
    const float rs = 0.044194173824159216f;  // 1/sqrt(512)
    unsigned short qs[32], ks[32];
#pragma unroll
    for (int dq = 0; dq < 8; ++dq) {
      float4 cc = c4[dq], ss = s4[dq];
      float qa = (dq < 4) ? qa0 : qa1, qp = (dq < 4) ? qp0 : qp1;
      float ka = (dq < 4) ? ka0 : ka1, kp = (dq < 4) ? kp0 : kp1;
      qs[dq * 4 + 0] = f2bf((qa * cc.x + sg * qp * ss.x) * rs);
      qs[dq * 4 + 1] = f2bf((qa * cc.y + sg * qp * ss.y) * rs);
      qs[dq * 4 + 2] = f2bf((qa * cc.z + sg * qp * ss.z) * rs);
      qs[dq * 4 + 3] = f2bf((qa * cc.w + sg * qp * ss.w) * rs);
      ks[dq * 4 + 0] = f2bf(ka * cc.x + sg * kp * ss.x);
      ks[dq * 4 + 1] = f2bf(ka * cc.y + sg * kp * ss.y);
      ks[dq * 4 + 2] = f2bf(ka * cc.z + sg * kp * ss.z);
      ks[dq * 4 + 3] = f2bf(ka * cc.w + sg * kp * ss.w);
    }
#pragma unroll
    for (int q4 = 0; q4 < 4; ++q4) {
      *(u16x8*)&qtile[t * 32 + q4 * 8] = *(u16x8*)&qs[q4 * 8];
      *(u16x8*)&Kb[t * 32 + q4 * 8] = *(u16x8*)&ks[q4 * 8];
    }
  }
  __syncthreads();

  const int wv = t >> 6, lane = t & 63;
  const int lm = lane & 15, lq = lane >> 4;
  const int kq = lq * 8;
  const size_t abase = (size_t)unit * 65536;
  float* stw = &stage[wv][0];

  // preload this lane's 4 Q-fragments (32 VGPR), then release stage buffer
  bf16x8 bQf[4];
#pragma unroll
  for (int mt = 0; mt < 4; ++mt)
    bQf[mt] = *(const bf16x8*)&qtile[((wv * 4 + mt) * 16 + lm) * 32 + kq];
  __syncthreads();  // qtile dead; stage becomes per-wave P staging

#pragma unroll
  for (int mt = 0; mt < 4; ++mt) {
    const int iT = wv * 4 + mt;
    const int i = iT * 16 + lm;  // this lane's query row

    // ---- pass A: stats only (one MFMA result live at a time) ----
    float ls = 0.f, pa = 0.f, pb = 0.f;
#pragma unroll
    for (int nt = 0; nt < 16; ++nt) {
      bf16x8 aK = *(const bf16x8*)&Kb[(nt * 16 + lm) * 32 + kq];
      f32x4 z = {0.f, 0.f, 0.f, 0.f};
      f32x4 s4 = __builtin_amdgcn_mfma_f32_16x16x32_bf16(aK, bQf[mt], z, 0, 0, 0);
      float4 v01 = *(const float4*)&vpair[nt * 32 + lq * 8];
      float4 v23 = *(const float4*)&vpair[nt * 32 + lq * 8 + 4];
      const int j0 = nt * 16 + lq * 4;
      float e0 = __expf((j0 + 0 <= i) ? s4[0] : 0.f);
      float e1 = __expf((j0 + 1 <= i) ? s4[1] : 0.f);
      float e2 = __expf((j0 + 2 <= i) ? s4[2] : 0.f);
      float e3 = __expf((j0 + 3 <= i) ? s4[3] : 0.f);
      ls += (e0 + e1) + (e2 + e3);
      pa += e0 * v01.x + e1 * v01.z + e2 * v23.x + e3 * v23.z;
      pb += e0 * v01.y + e1 * v01.w + e2 * v23.y + e3 * v23.w;
    }
    ls += __shfl_xor(ls, 16);
    ls += __shfl_xor(ls, 32);
    pa += __shfl_xor(pa, 16);
    pa += __shfl_xor(pa, 32);
    pb += __shfl_xor(pb, 16);
    pb += __shfl_xor(pb, 32);
    const float invl = 1.f / ls;

    if (lq == 0) {  // pv row entry: cols g*32 + h*2 + {0,1}
      u16x2 pvv = {f2bf(pa * invl), f2bf(pb * invl)};
      *(u16x2*)&pv_out[(size_t)(b * 4096 + w * 256 + i) * 128 + g * 32 + h * 2] = pvv;
    }

    // ---- pass B: recompute per 64-col chunk, stage, coalesced NT flush ----
#pragma unroll
    for (int nc = 0; nc < 4; ++nc) {
#pragma unroll
      for (int nt2 = 0; nt2 < 4; ++nt2) {
        int nt = nc * 4 + nt2;
        bf16x8 aK = *(const bf16x8*)&Kb[(nt * 16 + lm) * 32 + kq];
        f32x4 z = {0.f, 0.f, 0.f, 0.f};
        f32x4 s4 = __builtin_amdgcn_mfma_f32_16x16x32_bf16(aK, bQf[mt], z, 0, 0, 0);
        const int j0 = nt * 16 + lq * 4;
        f32x4 p4;
        p4[0] = __expf((j0 + 0 <= i) ? s4[0] : 0.f) * invl;
        p4[1] = __expf((j0 + 1 <= i) ? s4[1] : 0.f) * invl;
        p4[2] = __expf((j0 + 2 <= i) ? s4[2] : 0.f) * invl;
        p4[3] = __expf((j0 + 3 <= i) ? s4[3] : 0.f) * invl;
        int phys = (nt2 * 4 + lq + lm) & 15;  // rotate-slot swizzle
        *(f32x4*)&stw[lm * 68 + phys * 4] = p4;
      }
      asm volatile("s_waitcnt lgkmcnt(0)" ::: "memory");
      __builtin_amdgcn_sched_barrier(0);
#pragma unroll
      for (int rb = 0; rb < 4; ++rb) {
        int rr = rb * 4 + lq;   // row within tile
        int c = lm;             // 16B slot within 64-col chunk
        int phys = (c + rr) & 15;
        f32x4 pvv = *(const f32x4*)&stw[rr * 68 + phys * 4];
        f32x4* gp = (f32x4*)&attn_out[abase + (size_t)(iT * 16 + rr) * 256 + nc * 64 + c * 4];
        __builtin_nontemporal_store(pvv, gp);
      }
      asm volatile("s_waitcnt lgkmcnt(0)" ::: "memory");
      __builtin_amdgcn_sched_barrier(0);
    }
  }
}

extern "C" void kernel_launch(void* const* d_in, const int* in_sizes, int n_in,
                              void* d_out, int out_size, void* d_ws, size_t ws_size,
                              hipStream_t stream) {
  const float* inputs  = (const float*)d_in[0];
  const float* context = (const float*)d_in[1];
  const float* Wq = (const float*)d_in[3];
  const float* bq = (const float*)d_in[4];
  const float* Wk = (const float*)d_in[5];
  const float* bk = (const float*)d_in[6];
  const float* Wv = (const float*)d_in[7];
  const float* bv = (const float*)d_in[8];
  const float* Wo = (const float*)d_in[9];
  const float* bo = (const float*)d_in[10];
  float* out = (float*)d_out;
  float* attn_out = out + 16777216;

  char* wsb = (char*)d_ws;
  size_t o = 0;
  float* cosT = (float*)(wsb + o);            o += 4194304;
  float* sinT = (float*)(wsb + o);            o += 4194304;
  unsigned short* WqT  = (unsigned short*)(wsb + o); o += 524288;   // 128x2048 bf16
  unsigned short* WkvT = (unsigned short*)(wsb + o); o += 524288;   // 128x2048 (rows 64+ stale, unused)
  unsigned short* WoR  = (unsigned short*)(wsb + o); o += 524288;   // 2048x128 bf16 reduced Wo
  float* qbufA  = (float*)(wsb + o);          o += 4194304;
  float* qbufB  = (float*)(wsb + o);          o += 4194304;
  float* kvbufA = (float*)(wsb + o);          o += 4194304;
  float* kvbufB = (float*)(wsb + o);          o += 4194304;
  unsigned short* pv = (unsigned short*)(wsb + o); o += 2097152;    // 8192x128 bf16
  float* biaskv = (float*)(wsb + o);          o += 512;

  k_prep<<<5505, 256, 0, stream>>>(cosT, sinT, Wq, Wk, Wv, WqT, WkvT, Wo, WoR,
                                   bk, bv, biaskv);

  // split-K=2 QKV: y = K-half, z = problem (q / kv)
  k_qkv<<<dim3(256, 2, 2), 256, 0, stream>>>(
      inputs, WqT, qbufA, qbufB, bq, context, WkvT, kvbufA, kvbufB, biaskv, 2048);

  k_attn<<<2048, 256, 0, stream>>>(qbufA, qbufB, kvbufA, kvbufB,
                                   cosT, sinT, attn_out, pv);

  // out = pv @ WoR + bo: M=8192 N=2048 K=128 (16x reduced)
  k_gemm<128, 128><<<dim3(64, 16), 256, 0, stream>>>(pv, WoR, out, bo, 8192, 2048, 128);
}